// Round 8
// baseline (241.647 us; speedup 1.0000x reference)
//
#include <hip/hip_runtime.h>
#include <math.h>

// Damping: B=32768, N=64, H=256, OFF=2016
//   diag: x -> tanh(Wd1) -> tanh(Wd2) -> Wdo   (64 per sample)
//   off : x -> tanh(Wo1) -> tanh(Wo2) -> Woo   (2016 per sample, strict lower tri)
//   out = L (L^T x0), L diag = xd, L[i][j](j<i) = z[i(i-1)/2+j]
//
// z path: gemm_z (m97-style 128x128 LDS-staged GEMM) -> HBM in padded-triangle
// pair-interleaved groups of 32 samples -> apply kernel stages one group in LDS.

#define B_TOT 32768
#define NDIM  64
#define HDIM  256
#define OFFD  2016
#define QS    8192                 // samples per quarter
#define GRP_UNITS 67584            // 16 pairs * 4224 units (bf16) per 32-sample group
#define GRP_BYTES 135168

typedef __bf16 bf16x8 __attribute__((ext_vector_type(8)));
typedef float  f32x4  __attribute__((ext_vector_type(4)));

__device__ __forceinline__ float fast_tanh(float x) {
  float e = __expf(2.f * x);
  return 1.f - 2.f * __builtin_amdgcn_rcpf(e + 1.f);
}
__device__ __forceinline__ float lane_bcast(float v, int l) {
  return __uint_as_float(__builtin_amdgcn_readlane(__float_as_uint(v), l));
}
__device__ __forceinline__ float bf_lo(unsigned w) { return __uint_as_float(w << 16); }
__device__ __forceinline__ float bf_hi(unsigned w) { return __uint_as_float(w & 0xffff0000u); }

__device__ __forceinline__ void gload_lds16(const void* g, void* l) {
  __builtin_amdgcn_global_load_lds(
      (const __attribute__((address_space(1))) unsigned*)g,
      (__attribute__((address_space(3))) unsigned*)l, 16, 0, 0);
}

// ---------------- weight cast (f32 -> bf16) + Woob pad zero-fill ----------------
__device__ __forceinline__ void cast_range(const float* __restrict__ s,
                                           __bf16* __restrict__ d, int n) {
  int i = blockIdx.x * blockDim.x + threadIdx.x;
  const int stride = gridDim.x * blockDim.x;
  for (; i < n; i += stride) d[i] = (__bf16)s[i];
}
__global__ __launch_bounds__(256) void cast_all_kernel(
    const float* s0, __bf16* d0, int n0, const float* s1, __bf16* d1, int n1,
    const float* s2, __bf16* d2, int n2, const float* s3, __bf16* d3, int n3,
    const float* s4, __bf16* d4, int n4, const float* s5, __bf16* d5, int n5,
    __bf16* d6, int n6) {
  cast_range(s0, d0, n0); cast_range(s1, d1, n1); cast_range(s2, d2, n2);
  cast_range(s3, d3, n3); cast_range(s4, d4, n4); cast_range(s5, d5, n5);
  int i = blockIdx.x * blockDim.x + threadIdx.x;
  const int stride = gridDim.x * blockDim.x;
  for (; i < n6; i += stride) d6[i] = (__bf16)0.f;
}

__device__ __forceinline__ bf16x8 cvt8(const float* __restrict__ p) {
  const float4 u = *(const float4*)p;
  const float4 v = *(const float4*)(p + 4);
  bf16x8 r;
  r[0] = (__bf16)u.x; r[1] = (__bf16)u.y; r[2] = (__bf16)u.z; r[3] = (__bf16)u.w;
  r[4] = (__bf16)v.x; r[5] = (__bf16)v.y; r[6] = (__bf16)v.z; r[7] = (__bf16)v.w;
  return r;
}

#define MFMA(A, B, C) __builtin_amdgcn_mfma_f32_16x16x32_bf16((A), (B), (C), 0, 0, 0)
#define SB0() __builtin_amdgcn_sched_barrier(0)

// 8 named B loads (V##0..V##7), stride 32 ch (64 B)
#define LDB8V(V, P)                                   \
  const bf16x8 V##0 = *(const bf16x8*)(P);            \
  const bf16x8 V##1 = *(const bf16x8*)((P) + 32);     \
  const bf16x8 V##2 = *(const bf16x8*)((P) + 64);     \
  const bf16x8 V##3 = *(const bf16x8*)((P) + 96);     \
  const bf16x8 V##4 = *(const bf16x8*)((P) + 128);    \
  const bf16x8 V##5 = *(const bf16x8*)((P) + 160);    \
  const bf16x8 V##6 = *(const bf16x8*)((P) + 192);    \
  const bf16x8 V##7 = *(const bf16x8*)((P) + 224);

// 8 named A reads (a0..a7) from chunked LDS, stride 1024 units per ks
#define LDA8(P)                                     \
  const bf16x8 a0 = *(const bf16x8*)(P);            \
  const bf16x8 a1 = *(const bf16x8*)((P) + 1024);   \
  const bf16x8 a2 = *(const bf16x8*)((P) + 2048);   \
  const bf16x8 a3 = *(const bf16x8*)((P) + 3072);   \
  const bf16x8 a4 = *(const bf16x8*)((P) + 4096);   \
  const bf16x8 a5 = *(const bf16x8*)((P) + 5120);   \
  const bf16x8 a6 = *(const bf16x8*)((P) + 6144);   \
  const bf16x8 a7 = *(const bf16x8*)((P) + 7168);

#define MFMA8V(ACC, B)              \
  ACC = MFMA(a0, B##0, ACC);        \
  ACC = MFMA(a1, B##1, ACC);        \
  ACC = MFMA(a2, B##2, ACC);        \
  ACC = MFMA(a3, B##3, ACC);        \
  ACC = MFMA(a4, B##4, ACC);        \
  ACC = MFMA(a5, B##5, ACC);        \
  ACC = MFMA(a6, B##6, ACC);        \
  ACC = MFMA(a7, B##7, ACC);

// ---------------- K1: both MLP trunks, 32 samples / WG, 8 waves ----------------
__global__ __launch_bounds__(512, 4) void trunk_kernel(
    const float* __restrict__ x, const __bf16* __restrict__ W1,
    const float* __restrict__ bd1, const float* __restrict__ bo1,
    const __bf16* __restrict__ Wd2, const float* __restrict__ bd2,
    const __bf16* __restrict__ Wdo, const float* __restrict__ bdo,
    const __bf16* __restrict__ Wo2, const float* __restrict__ bo2,
    __bf16* __restrict__ g2, float* __restrict__ xd) {
  __shared__ __bf16 ch512[64 * 256];  // 32 KB
  __shared__ __bf16 buf2[32 * 256];   // 16 KB
  const int tid = threadIdx.x;
  const int wave = tid >> 6, lane = tid & 63;
  const int lr = lane & 15, lg = lane >> 4;
  const int sb = blockIdx.x * 32;

  const float* xb = x + (size_t)(sb + lr) * NDIM + lg * 8;
  const bf16x8 ax00 = cvt8(xb);
  const bf16x8 ax01 = cvt8(xb + 32);
  const bf16x8 ax10 = cvt8(xb + 16 * NDIM);
  const bf16x8 ax11 = cvt8(xb + 16 * NDIM + 32);

  {
    const __bf16* w1p = W1 + (wave * 16 + lr) * NDIM + lg * 8;
    const bf16x8 p00 = *(const bf16x8*)(w1p);
    const bf16x8 p01 = *(const bf16x8*)(w1p + 32);
    const bf16x8 p10 = *(const bf16x8*)(w1p + 128 * NDIM);
    const bf16x8 p11 = *(const bf16x8*)(w1p + 128 * NDIM + 32);
    const bf16x8 p20 = *(const bf16x8*)(w1p + 256 * NDIM);
    const bf16x8 p21 = *(const bf16x8*)(w1p + 256 * NDIM + 32);
    const bf16x8 p30 = *(const bf16x8*)(w1p + 384 * NDIM);
    const bf16x8 p31 = *(const bf16x8*)(w1p + 384 * NDIM + 32);
    SB0();
#define L1TILE(B0, B1, A0, A1, NB, MROW)                                         \
    {                                                                            \
      f32x4 acc = {0.f, 0.f, 0.f, 0.f};                                          \
      acc = MFMA(A0, B0, acc);                                                   \
      acc = MFMA(A1, B1, acc);                                                   \
      const int ch = (NB) * 16 + lr;                                             \
      const float bv = (ch < 256) ? bd1[ch] : bo1[ch - 256];                     \
      _Pragma("unroll")                                                          \
      for (int r = 0; r < 4; ++r) {                                              \
        const int s = (MROW) + lg * 4 + r;                                       \
        ch512[(ch >> 3) * 256 + s * 8 + (ch & 7)] = (__bf16)fast_tanh(acc[r] + bv); \
      }                                                                          \
    }
    L1TILE(p00, p01, ax00, ax01, wave, 0)
    L1TILE(p10, p11, ax00, ax01, wave + 8, 0)
    L1TILE(p20, p21, ax00, ax01, wave + 16, 0)
    L1TILE(p30, p31, ax00, ax01, wave + 24, 0)
    L1TILE(p00, p01, ax10, ax11, wave, 16)
    L1TILE(p10, p11, ax10, ax11, wave + 8, 16)
    L1TILE(p20, p21, ax10, ax11, wave + 16, 16)
    L1TILE(p30, p31, ax10, ax11, wave + 24, 16)
  }
  __syncthreads();

  {
    LDB8V(p, Wd2 + (wave * 16 + lr) * HDIM + lg * 8)
    LDB8V(q, Wd2 + ((wave + 8) * 16 + lr) * HDIM + lg * 8)
    SB0();
#define L2STORE_BUF(ACC, NB, MROW)                                               \
    {                                                                            \
      const int ch = (NB) * 16 + lr;                                             \
      const float bv = bd2[ch];                                                  \
      _Pragma("unroll")                                                          \
      for (int r = 0; r < 4; ++r) {                                              \
        const int s = (MROW) + lg * 4 + r;                                       \
        buf2[(ch >> 3) * 256 + s * 8 + (ch & 7)] = (__bf16)fast_tanh(ACC[r] + bv); \
      }                                                                          \
    }
    {
      LDA8(ch512 + lr * 8 + lg * 256)
      f32x4 accp = {0.f, 0.f, 0.f, 0.f}, accq = {0.f, 0.f, 0.f, 0.f};
      MFMA8V(accp, p)
      MFMA8V(accq, q)
      L2STORE_BUF(accp, wave, 0)
      L2STORE_BUF(accq, wave + 8, 0)
    }
    {
      LDA8(ch512 + (16 + lr) * 8 + lg * 256)
      f32x4 accp = {0.f, 0.f, 0.f, 0.f}, accq = {0.f, 0.f, 0.f, 0.f};
      MFMA8V(accp, p)
      MFMA8V(accq, q)
      L2STORE_BUF(accp, wave, 16)
      L2STORE_BUF(accq, wave + 8, 16)
    }
  }
  {
    LDB8V(p, Wo2 + (wave * 16 + lr) * HDIM + lg * 8)
    LDB8V(q, Wo2 + ((wave + 8) * 16 + lr) * HDIM + lg * 8)
    SB0();
#define L2STORE_G2(ACC, NB, MROW)                                                \
    {                                                                            \
      const int ch = (NB) * 16 + lr;                                             \
      const float bv = bo2[ch];                                                  \
      _Pragma("unroll")                                                          \
      for (int r = 0; r < 4; ++r) {                                              \
        const int s = (MROW) + lg * 4 + r;                                       \
        g2[(size_t)(sb + s) * HDIM + ch] = (__bf16)fast_tanh(ACC[r] + bv);       \
      }                                                                          \
    }
    {
      LDA8(ch512 + 8192 + lr * 8 + lg * 256)
      f32x4 accp = {0.f, 0.f, 0.f, 0.f}, accq = {0.f, 0.f, 0.f, 0.f};
      MFMA8V(accp, p)
      MFMA8V(accq, q)
      L2STORE_G2(accp, wave, 0)
      L2STORE_G2(accq, wave + 8, 0)
    }
    {
      LDA8(ch512 + 8192 + (16 + lr) * 8 + lg * 256)
      f32x4 accp = {0.f, 0.f, 0.f, 0.f}, accq = {0.f, 0.f, 0.f, 0.f};
      MFMA8V(accp, p)
      MFMA8V(accq, q)
      L2STORE_G2(accp, wave, 16)
      L2STORE_G2(accq, wave + 8, 16)
    }
  }
  __syncthreads();

  {
    const int mrow = (wave >> 2) * 16;
    const int ch = (wave & 3) * 16 + lr;
    LDB8V(p, Wdo + ch * HDIM + lg * 8)
    SB0();
    LDA8(buf2 + (mrow + lr) * 8 + lg * 256)
    f32x4 acc = {0.f, 0.f, 0.f, 0.f};
    MFMA8V(acc, p)
    const float bv = bdo[ch];
#pragma unroll
    for (int r = 0; r < 4; ++r) {
      const int s = mrow + lg * 4 + r;
      xd[(size_t)(sb + s) * NDIM + ch] = acc[r] + bv;
    }
  }
}

// ---------------- gemm_z: z[8192 x 2016] = G @ Woo^T + boo  (per quarter) -------
// 128x128 tiles, BK=64, 4 waves, global_load_lds double-buffer, XOR-swizzled LDS.
// Epilogue scatters bf16 into padded-triangle pair-interleaved groups + pad zeros.
__global__ __launch_bounds__(256, 2) void gemm_z_kernel(
    const __bf16* __restrict__ g2q, const __bf16* __restrict__ Woob,
    const float* __restrict__ boo, __bf16* __restrict__ zq) {
  __shared__ __bf16 As[2][128 * 64];   // 16 KB each
  __shared__ __bf16 Bs[2][128 * 64];
  const int tid = threadIdx.x;
  const int wave = tid >> 6, lane = tid & 63;
  const int lr = lane & 15, lg = lane >> 4;

  // XCD swizzle: nwg=1024, cpx=128; consecutive swz share bn (B-panel per XCD)
  const int bid = blockIdx.x;
  const int swz = (bid & 7) * 128 + (bid >> 3);
  const int bm = swz & 63, bn = swz >> 6;

  const int lrow = wave * 32 + (lane >> 3);  // + j*8
  const int lchunk = lane & 7;

#define STAGE_TILE(BUF, KT)                                                       \
  {                                                                               \
    _Pragma("unroll")                                                             \
    for (int j = 0; j < 4; ++j) {                                                 \
      const int ra = lrow + j * 8;                                                \
      const int ka = (KT) * 64 + ((lchunk ^ (ra & 7)) << 3);                      \
      gload_lds16(g2q + (size_t)(bm * 128 + ra) * 256 + ka,                       \
                  As[BUF] + wave * 2048 + j * 512);                               \
      gload_lds16(Woob + (size_t)(bn * 128 + ra) * 256 + ka,                      \
                  Bs[BUF] + wave * 2048 + j * 512);                               \
    }                                                                             \
  }

  f32x4 acc[4][4];
#pragma unroll
  for (int i = 0; i < 4; ++i)
#pragma unroll
    for (int j = 0; j < 4; ++j) acc[i][j] = (f32x4){0.f, 0.f, 0.f, 0.f};

  STAGE_TILE(0, 0)
  __syncthreads();
  int cur = 0;
#pragma unroll
  for (int kt = 0; kt < 4; ++kt) {
    if (kt < 3) STAGE_TILE(cur ^ 1, kt + 1)
    const __bf16* Ab = As[cur];
    const __bf16* Bb = Bs[cur];
#pragma unroll
    for (int ks = 0; ks < 2; ++ks) {
      bf16x8 af[4], bfg[4];
#pragma unroll
      for (int f = 0; f < 4; ++f) {
        const int rowA = (wave >> 1) * 64 + f * 16 + lr;
        af[f] = *(const bf16x8*)(Ab + rowA * 64 + (((ks * 4 + lg) ^ (lr & 7)) << 3));
        const int rowB = (wave & 1) * 64 + f * 16 + lr;
        bfg[f] = *(const bf16x8*)(Bb + rowB * 64 + (((ks * 4 + lg) ^ (lr & 7)) << 3));
      }
#pragma unroll
      for (int fr = 0; fr < 4; ++fr)
#pragma unroll
        for (int fc = 0; fc < 4; ++fc)
          acc[fr][fc] = MFMA(af[fr], bfg[fc], acc[fr][fc]);
    }
    if (kt < 3) __syncthreads();
    cur ^= 1;
  }

  // epilogue: scatter into padded-triangle pair-interleaved z (+ pad zeros)
#pragma unroll
  for (int fc = 0; fc < 4; ++fc) {
    const int col = bn * 128 + (wave & 1) * 64 + fc * 16 + lr;
    if (col < OFFD) {
      const float sq = sqrtf((float)(1 + 8 * col));
      const int i = (int)((1.f + sq) * 0.5f);
      const int tri = (i * (i - 1)) >> 1;
      const int r3 = i & 3;
      const int offv =
          tri + 6 * (i >> 2) + ((r3 == 2) ? 3 : (r3 == 3) ? 5 : 0) + (col - tri);
      const float bv = boo[col];
      const int padcnt = (4 - r3) & 3;
      const bool lastcol = (col == tri + i - 1);
#pragma unroll
      for (int fr = 0; fr < 4; ++fr) {
#pragma unroll
        for (int r = 0; r < 4; ++r) {
          const int srow = bm * 128 + (wave >> 1) * 64 + fr * 16 + lg * 4 + r;
          const int grp = srow >> 5, sig = srow & 31;
          const size_t pbase = (size_t)grp * GRP_UNITS + (sig >> 1) * 4224;
          zq[pbase + (size_t)offv * 2 + (sig & 1)] = (__bf16)(acc[fr][fc][r] + bv);
          if (lastcol && padcnt && ((r & 1) == 0)) {
            unsigned* pz = (unsigned*)(zq + pbase + (size_t)(offv + 1) * 2);
#pragma unroll
            for (int d = 0; d < 3; ++d)
              if (d < padcnt) pz[d] = 0u;
          }
        }
      }
    }
  }
}

// ---------------- apply: stage one 32-sample z group, two triangular passes -----
#define APPLY_SMEM (GRP_BYTES + 8192)
__global__ __launch_bounds__(1024, 4) void apply_kernel(
    const __bf16* __restrict__ zq, const float* __restrict__ xd,
    const float* __restrict__ x0, float* __restrict__ out, int s0base) {
  extern __shared__ char smem[];
  __bf16* ztb = (__bf16*)smem;            // unit: pair*4224 + off*2 + slot
  float* ys2 = (float*)(smem + GRP_BYTES);

  const int tid = threadIdx.x;
  const int wave = tid >> 6, lane = tid & 63;
  const int sb = s0base + blockIdx.x * 32;

  // flat stage of the group (135168 B) via global_load_lds
  const char* gsrc = (const char*)zq + (size_t)blockIdx.x * GRP_BYTES;
#pragma unroll
  for (int sweep = 0; sweep < 9; ++sweep) {
    if (sweep < 8 || wave < 4) {
      const int off = sweep * 16384 + wave * 1024;
      gload_lds16(gsrc + off + lane * 16, smem + off);
    }
  }
  __syncthreads();

  const int s0 = wave * 2, s1 = s0 + 1;
  const __bf16* zpair = ztb + wave * 4224;
  const float x0vA = x0[(size_t)(sb + s0) * 64 + lane];
  const float x0vB = x0[(size_t)(sb + s1) * 64 + lane];
  const float xdA = xd[(size_t)(sb + s0) * 64 + lane];
  const float xdB = xd[(size_t)(sb + s1) * 64 + lane];

  // pass 1: y_j = xd_j x0_j + sum_{k>j} z[k][j] x0_k
  float yA = xdA * x0vA, yB = xdB * x0vB;
  int rs = 0;
#pragma unroll
  for (int k = 1; k < 64; ++k) {
    const unsigned w = *(const unsigned*)(zpair + (rs + lane) * 2);
    const float xkA = lane_bcast(x0vA, k);
    const float xkB = lane_bcast(x0vB, k);
    const bool mvalid = lane < k;
    yA += mvalid ? bf_lo(w) * xkA : 0.f;
    yB += mvalid ? bf_hi(w) * xkB : 0.f;
    rs += (k + 3) & ~3;
  }

  float* yp = ys2 + wave * 128;
  *(float2*)(yp + lane * 2) = make_float2(yA, yB);

  // pass 2: D_i = xd_i y_i + sum_{j<i} z[i][j] y_j  (zero pads absorb masks)
  float DA = xdA * yA, DB = xdB * yB;
  float dA1 = 0.f, dB1 = 0.f;
  {
    const int r3 = lane & 3;
    const int rsi = ((lane * (lane - 1)) >> 1) + 6 * (lane >> 2) +
                    ((r3 == 2) ? 3 : (r3 == 3) ? 5 : 0);
    const int cmax = (lane + 3) >> 2;
    const __bf16* zrow = zpair + rsi * 2;
#pragma unroll 4
    for (int c = 0; c < cmax; ++c) {
      const uint4 w = *(const uint4*)(zrow + c * 8);
      const float4 u0 = *(const float4*)(yp + c * 8);
      const float4 u1 = *(const float4*)(yp + c * 8 + 4);
      DA += bf_lo(w.x) * u0.x + bf_lo(w.z) * u1.x;
      dA1 += bf_lo(w.y) * u0.z + bf_lo(w.w) * u1.z;
      DB += bf_hi(w.x) * u0.y + bf_hi(w.z) * u1.y;
      dB1 += bf_hi(w.y) * u0.w + bf_hi(w.w) * u1.w;
    }
  }
  out[(size_t)(sb + s0) * 64 + lane] = DA + dA1;
  out[(size_t)(sb + s1) * 64 + lane] = DB + dB1;
}

// ---------------- launch ----------------
extern "C" void kernel_launch(void* const* d_in, const int* in_sizes, int n_in,
                              void* d_out, int out_size, void* d_ws, size_t ws_size,
                              hipStream_t stream) {
  const float* x   = (const float*)d_in[0];
  const float* Wd1 = (const float*)d_in[1];
  const float* bd1 = (const float*)d_in[2];
  const float* Wd2 = (const float*)d_in[3];
  const float* bd2 = (const float*)d_in[4];
  const float* Wdo = (const float*)d_in[5];
  const float* bdo = (const float*)d_in[6];
  const float* Wo1 = (const float*)d_in[7];
  const float* bo1 = (const float*)d_in[8];
  const float* Wo2 = (const float*)d_in[9];
  const float* bo2 = (const float*)d_in[10];
  const float* Woo = (const float*)d_in[11];
  const float* boo = (const float*)d_in[12];
  float* out = (float*)d_out;

  char* ws = (char*)d_ws;
  __bf16* W1b  = (__bf16*)(ws + 0);          //    65536 B (Wd1 | Wo1 rows)
  __bf16* Wd2b = (__bf16*)(ws + 65536);      //   131072 B
  __bf16* Wo2b = (__bf16*)(ws + 196608);     //   131072 B
  __bf16* Wdob = (__bf16*)(ws + 327680);     //    32768 B
  __bf16* Woob = (__bf16*)(ws + 360448);     //  1048576 B (2048 rows, padded)
  __bf16* g2   = (__bf16*)(ws + 1409024);    // 16777216 B
  float*  xdp  = (float*)(ws + 18186240);    //  8388608 B
  __bf16* zq   = (__bf16*)(ws + 26574848);   // 34603008 B (one quarter of z)
                                             // end 61177856

  cast_all_kernel<<<512, 256, 0, stream>>>(
      Wd1, W1b, HDIM * NDIM,
      Wo1, W1b + HDIM * NDIM, HDIM * NDIM,
      Wd2, Wd2b, HDIM * HDIM,
      Wo2, Wo2b, HDIM * HDIM,
      Wdo, Wdob, NDIM * HDIM,
      Woo, Woob, OFFD * HDIM,
      Woob + OFFD * HDIM, 32 * HDIM);

  trunk_kernel<<<B_TOT / 32, 512, 0, stream>>>(x, W1b, bd1, bo1, Wd2b, bd2, Wdob, bdo,
                                               Wo2b, bo2, g2, xdp);

  hipFuncSetAttribute((const void*)apply_kernel,
                      hipFuncAttributeMaxDynamicSharedMemorySize, APPLY_SMEM);
  for (int q = 0; q < 4; ++q) {
    gemm_z_kernel<<<(QS / 128) * 16, 256, 0, stream>>>(
        g2 + (size_t)q * QS * HDIM, Woob, boo, zq);
    apply_kernel<<<QS / 32, 1024, APPLY_SMEM, stream>>>(zq, xdp, x, out, q * QS);
  }
}

// Round 9
// 212.244 us; speedup vs baseline: 1.1385x; 1.1385x over previous
//
#include <hip/hip_runtime.h>
#include <math.h>

// Damping: B=32768, N=64, H=256, OFF=2016
//   diag: x -> tanh(Wd1) -> tanh(Wd2) -> Wdo   (64 per sample)
//   off : x -> tanh(Wo1) -> tanh(Wo2) -> Woo   (2016 per sample, strict lower tri)
//   out = L (L^T x0), L diag = xd, L[i][j](j<i) = z[i(i-1)/2+j]
//
// z path: gemm_z (256x256-tile LDS-staged GEMM) -> HBM padded-triangle
// pair-interleaved groups of 32 samples -> apply (wave-local stage + 2 passes).

#define B_TOT 32768
#define NDIM  64
#define HDIM  256
#define OFFD  2016
#define QS    8192                 // samples per quarter
#define GRP_UNITS 67584            // 16 pairs * 4224 units (bf16) per 32-sample group
#define GRP_BYTES 135168

typedef __bf16 bf16x8 __attribute__((ext_vector_type(8)));
typedef float  f32x4  __attribute__((ext_vector_type(4)));

__device__ __forceinline__ float fast_tanh(float x) {
  float e = __expf(2.f * x);
  return 1.f - 2.f * __builtin_amdgcn_rcpf(e + 1.f);
}
__device__ __forceinline__ float lane_bcast(float v, int l) {
  return __uint_as_float(__builtin_amdgcn_readlane(__float_as_uint(v), l));
}
__device__ __forceinline__ float bf_lo(unsigned w) { return __uint_as_float(w << 16); }
__device__ __forceinline__ float bf_hi(unsigned w) { return __uint_as_float(w & 0xffff0000u); }

__device__ __forceinline__ void gload_lds16(const void* g, void* l) {
  __builtin_amdgcn_global_load_lds(
      (const __attribute__((address_space(1))) unsigned*)g,
      (__attribute__((address_space(3))) unsigned*)l, 16, 0, 0);
}

// ---------------- weight cast (f32 -> bf16) + Woob pad zero-fill ----------------
__device__ __forceinline__ void cast_range(const float* __restrict__ s,
                                           __bf16* __restrict__ d, int n) {
  int i = blockIdx.x * blockDim.x + threadIdx.x;
  const int stride = gridDim.x * blockDim.x;
  for (; i < n; i += stride) d[i] = (__bf16)s[i];
}
__global__ __launch_bounds__(256) void cast_all_kernel(
    const float* s0, __bf16* d0, int n0, const float* s1, __bf16* d1, int n1,
    const float* s2, __bf16* d2, int n2, const float* s3, __bf16* d3, int n3,
    const float* s4, __bf16* d4, int n4, const float* s5, __bf16* d5, int n5,
    __bf16* d6, int n6) {
  cast_range(s0, d0, n0); cast_range(s1, d1, n1); cast_range(s2, d2, n2);
  cast_range(s3, d3, n3); cast_range(s4, d4, n4); cast_range(s5, d5, n5);
  int i = blockIdx.x * blockDim.x + threadIdx.x;
  const int stride = gridDim.x * blockDim.x;
  for (; i < n6; i += stride) d6[i] = (__bf16)0.f;
}

__device__ __forceinline__ bf16x8 cvt8(const float* __restrict__ p) {
  const float4 u = *(const float4*)p;
  const float4 v = *(const float4*)(p + 4);
  bf16x8 r;
  r[0] = (__bf16)u.x; r[1] = (__bf16)u.y; r[2] = (__bf16)u.z; r[3] = (__bf16)u.w;
  r[4] = (__bf16)v.x; r[5] = (__bf16)v.y; r[6] = (__bf16)v.z; r[7] = (__bf16)v.w;
  return r;
}

#define MFMA(A, B, C) __builtin_amdgcn_mfma_f32_16x16x32_bf16((A), (B), (C), 0, 0, 0)
#define SB0() __builtin_amdgcn_sched_barrier(0)

// 8 named B loads (V##0..V##7), stride 32 ch (64 B)
#define LDB8V(V, P)                                   \
  const bf16x8 V##0 = *(const bf16x8*)(P);            \
  const bf16x8 V##1 = *(const bf16x8*)((P) + 32);     \
  const bf16x8 V##2 = *(const bf16x8*)((P) + 64);     \
  const bf16x8 V##3 = *(const bf16x8*)((P) + 96);     \
  const bf16x8 V##4 = *(const bf16x8*)((P) + 128);    \
  const bf16x8 V##5 = *(const bf16x8*)((P) + 160);    \
  const bf16x8 V##6 = *(const bf16x8*)((P) + 192);    \
  const bf16x8 V##7 = *(const bf16x8*)((P) + 224);

// 8 named A reads (a0..a7) from chunked LDS, stride 1024 units per ks
#define LDA8(P)                                     \
  const bf16x8 a0 = *(const bf16x8*)(P);            \
  const bf16x8 a1 = *(const bf16x8*)((P) + 1024);   \
  const bf16x8 a2 = *(const bf16x8*)((P) + 2048);   \
  const bf16x8 a3 = *(const bf16x8*)((P) + 3072);   \
  const bf16x8 a4 = *(const bf16x8*)((P) + 4096);   \
  const bf16x8 a5 = *(const bf16x8*)((P) + 5120);   \
  const bf16x8 a6 = *(const bf16x8*)((P) + 6144);   \
  const bf16x8 a7 = *(const bf16x8*)((P) + 7168);

#define MFMA8V(ACC, B)              \
  ACC = MFMA(a0, B##0, ACC);        \
  ACC = MFMA(a1, B##1, ACC);        \
  ACC = MFMA(a2, B##2, ACC);        \
  ACC = MFMA(a3, B##3, ACC);        \
  ACC = MFMA(a4, B##4, ACC);        \
  ACC = MFMA(a5, B##5, ACC);        \
  ACC = MFMA(a6, B##6, ACC);        \
  ACC = MFMA(a7, B##7, ACC);

// ---------------- K1: both MLP trunks, 32 samples / WG, 8 waves ----------------
__global__ __launch_bounds__(512, 4) void trunk_kernel(
    const float* __restrict__ x, const __bf16* __restrict__ W1,
    const float* __restrict__ bd1, const float* __restrict__ bo1,
    const __bf16* __restrict__ Wd2, const float* __restrict__ bd2,
    const __bf16* __restrict__ Wdo, const float* __restrict__ bdo,
    const __bf16* __restrict__ Wo2, const float* __restrict__ bo2,
    __bf16* __restrict__ g2, float* __restrict__ xd) {
  __shared__ __bf16 ch512[64 * 256];  // 32 KB
  __shared__ __bf16 buf2[32 * 256];   // 16 KB
  const int tid = threadIdx.x;
  const int wave = tid >> 6, lane = tid & 63;
  const int lr = lane & 15, lg = lane >> 4;
  const int sb = blockIdx.x * 32;

  const float* xb = x + (size_t)(sb + lr) * NDIM + lg * 8;
  const bf16x8 ax00 = cvt8(xb);
  const bf16x8 ax01 = cvt8(xb + 32);
  const bf16x8 ax10 = cvt8(xb + 16 * NDIM);
  const bf16x8 ax11 = cvt8(xb + 16 * NDIM + 32);

  {
    const __bf16* w1p = W1 + (wave * 16 + lr) * NDIM + lg * 8;
    const bf16x8 p00 = *(const bf16x8*)(w1p);
    const bf16x8 p01 = *(const bf16x8*)(w1p + 32);
    const bf16x8 p10 = *(const bf16x8*)(w1p + 128 * NDIM);
    const bf16x8 p11 = *(const bf16x8*)(w1p + 128 * NDIM + 32);
    const bf16x8 p20 = *(const bf16x8*)(w1p + 256 * NDIM);
    const bf16x8 p21 = *(const bf16x8*)(w1p + 256 * NDIM + 32);
    const bf16x8 p30 = *(const bf16x8*)(w1p + 384 * NDIM);
    const bf16x8 p31 = *(const bf16x8*)(w1p + 384 * NDIM + 32);
    SB0();
#define L1TILE(B0, B1, A0, A1, NB, MROW)                                         \
    {                                                                            \
      f32x4 acc = {0.f, 0.f, 0.f, 0.f};                                          \
      acc = MFMA(A0, B0, acc);                                                   \
      acc = MFMA(A1, B1, acc);                                                   \
      const int ch = (NB) * 16 + lr;                                             \
      const float bv = (ch < 256) ? bd1[ch] : bo1[ch - 256];                     \
      _Pragma("unroll")                                                          \
      for (int r = 0; r < 4; ++r) {                                              \
        const int s = (MROW) + lg * 4 + r;                                       \
        ch512[(ch >> 3) * 256 + s * 8 + (ch & 7)] = (__bf16)fast_tanh(acc[r] + bv); \
      }                                                                          \
    }
    L1TILE(p00, p01, ax00, ax01, wave, 0)
    L1TILE(p10, p11, ax00, ax01, wave + 8, 0)
    L1TILE(p20, p21, ax00, ax01, wave + 16, 0)
    L1TILE(p30, p31, ax00, ax01, wave + 24, 0)
    L1TILE(p00, p01, ax10, ax11, wave, 16)
    L1TILE(p10, p11, ax10, ax11, wave + 8, 16)
    L1TILE(p20, p21, ax10, ax11, wave + 16, 16)
    L1TILE(p30, p31, ax10, ax11, wave + 24, 16)
  }
  __syncthreads();

  {
    LDB8V(p, Wd2 + (wave * 16 + lr) * HDIM + lg * 8)
    LDB8V(q, Wd2 + ((wave + 8) * 16 + lr) * HDIM + lg * 8)
    SB0();
#define L2STORE_BUF(ACC, NB, MROW)                                               \
    {                                                                            \
      const int ch = (NB) * 16 + lr;                                             \
      const float bv = bd2[ch];                                                  \
      _Pragma("unroll")                                                          \
      for (int r = 0; r < 4; ++r) {                                              \
        const int s = (MROW) + lg * 4 + r;                                       \
        buf2[(ch >> 3) * 256 + s * 8 + (ch & 7)] = (__bf16)fast_tanh(ACC[r] + bv); \
      }                                                                          \
    }
    {
      LDA8(ch512 + lr * 8 + lg * 256)
      f32x4 accp = {0.f, 0.f, 0.f, 0.f}, accq = {0.f, 0.f, 0.f, 0.f};
      MFMA8V(accp, p)
      MFMA8V(accq, q)
      L2STORE_BUF(accp, wave, 0)
      L2STORE_BUF(accq, wave + 8, 0)
    }
    {
      LDA8(ch512 + (16 + lr) * 8 + lg * 256)
      f32x4 accp = {0.f, 0.f, 0.f, 0.f}, accq = {0.f, 0.f, 0.f, 0.f};
      MFMA8V(accp, p)
      MFMA8V(accq, q)
      L2STORE_BUF(accp, wave, 16)
      L2STORE_BUF(accq, wave + 8, 16)
    }
  }
  {
    LDB8V(p, Wo2 + (wave * 16 + lr) * HDIM + lg * 8)
    LDB8V(q, Wo2 + ((wave + 8) * 16 + lr) * HDIM + lg * 8)
    SB0();
#define L2STORE_G2(ACC, NB, MROW)                                                \
    {                                                                            \
      const int ch = (NB) * 16 + lr;                                             \
      const float bv = bo2[ch];                                                  \
      _Pragma("unroll")                                                          \
      for (int r = 0; r < 4; ++r) {                                              \
        const int s = (MROW) + lg * 4 + r;                                       \
        g2[(size_t)(sb + s) * HDIM + ch] = (__bf16)fast_tanh(ACC[r] + bv);       \
      }                                                                          \
    }
    {
      LDA8(ch512 + 8192 + lr * 8 + lg * 256)
      f32x4 accp = {0.f, 0.f, 0.f, 0.f}, accq = {0.f, 0.f, 0.f, 0.f};
      MFMA8V(accp, p)
      MFMA8V(accq, q)
      L2STORE_G2(accp, wave, 0)
      L2STORE_G2(accq, wave + 8, 0)
    }
    {
      LDA8(ch512 + 8192 + (16 + lr) * 8 + lg * 256)
      f32x4 accp = {0.f, 0.f, 0.f, 0.f}, accq = {0.f, 0.f, 0.f, 0.f};
      MFMA8V(accp, p)
      MFMA8V(accq, q)
      L2STORE_G2(accp, wave, 16)
      L2STORE_G2(accq, wave + 8, 16)
    }
  }
  __syncthreads();

  {
    const int mrow = (wave >> 2) * 16;
    const int ch = (wave & 3) * 16 + lr;
    LDB8V(p, Wdo + ch * HDIM + lg * 8)
    SB0();
    LDA8(buf2 + (mrow + lr) * 8 + lg * 256)
    f32x4 acc = {0.f, 0.f, 0.f, 0.f};
    MFMA8V(acc, p)
    const float bv = bdo[ch];
#pragma unroll
    for (int r = 0; r < 4; ++r) {
      const int s = mrow + lg * 4 + r;
      xd[(size_t)(sb + s) * NDIM + ch] = acc[r] + bv;
    }
  }
}

// ---------------- gemm_z: z[8192 x 2016] = G @ Woo^T + boo  (per quarter) -------
// 256x256 tiles, BK=64, 8 waves (each outputs 128x64), double-buffered
// global_load_lds staging with both-sides XOR swizzle. 128 KB dynamic LDS.
#define TILE_BYTES 32768
#define GEMM_SMEM  131072

__global__ __launch_bounds__(512, 2) void gemm_z_kernel(
    const __bf16* __restrict__ g2q, const __bf16* __restrict__ Woob,
    const float* __restrict__ boo, __bf16* __restrict__ zq) {
  extern __shared__ char gsm[];  // A: 0 / 32768 ; B: 65536 / 98304
  const int tid = threadIdx.x;
  const int wave = tid >> 6, lane = tid & 63;
  const int lr = lane & 15, lg = lane >> 4;
  const int bm = blockIdx.x & 31, bn = blockIdx.x >> 5;
  const int wr = wave >> 2, wc = wave & 3;
  const int srl = lane >> 3;     // 0..7 stage row within octet
  const int sch = lane & 7;      // stage chunk

#define STAGE(BUF, KT)                                                          \
  {                                                                             \
    _Pragma("unroll")                                                           \
    for (int j = 0; j < 4; ++j) {                                               \
      const int row = wave * 32 + j * 8 + srl;                                  \
      const int ka = (KT) * 64 + ((sch ^ (row & 7)) << 3);                      \
      gload_lds16(g2q + (size_t)(bm * 256 + row) * 256 + ka,                    \
                  gsm + (BUF) * TILE_BYTES + wave * 4096 + j * 1024);           \
      gload_lds16(Woob + (size_t)(bn * 256 + row) * 256 + ka,                   \
                  gsm + 65536 + (BUF) * TILE_BYTES + wave * 4096 + j * 1024);   \
    }                                                                           \
  }

  f32x4 acc[8][4];
#pragma unroll
  for (int i = 0; i < 8; ++i)
#pragma unroll
    for (int j = 0; j < 4; ++j) acc[i][j] = (f32x4){0.f, 0.f, 0.f, 0.f};

  STAGE(0, 0)
  __syncthreads();
#pragma unroll
  for (int kt = 0; kt < 4; ++kt) {
    if (kt < 3) STAGE((kt + 1) & 1, kt + 1)
    const __bf16* Ab = (const __bf16*)(gsm + (kt & 1) * TILE_BYTES);
    const __bf16* Bb = (const __bf16*)(gsm + 65536 + (kt & 1) * TILE_BYTES);
#pragma unroll
    for (int ks = 0; ks < 2; ++ks) {
      const int cc = ((ks * 4 + lg) ^ (lr & 7)) << 3;
      bf16x8 af[8];
#pragma unroll
      for (int fr = 0; fr < 8; ++fr)
        af[fr] = *(const bf16x8*)(Ab + (wr * 128 + fr * 16 + lr) * 64 + cc);
      bf16x8 bfr[4];
#pragma unroll
      for (int fc = 0; fc < 4; ++fc)
        bfr[fc] = *(const bf16x8*)(Bb + (wc * 64 + fc * 16 + lr) * 64 + cc);
#pragma unroll
      for (int fr = 0; fr < 8; ++fr)
#pragma unroll
        for (int fc = 0; fc < 4; ++fc)
          acc[fr][fc] = MFMA(af[fr], bfr[fc], acc[fr][fc]);
    }
    if (kt < 3) __syncthreads();
  }

  // epilogue: scatter into padded-triangle pair-interleaved z (+ pad zeros)
#pragma unroll
  for (int fc = 0; fc < 4; ++fc) {
    const int col = bn * 256 + wc * 64 + fc * 16 + lr;
    if (col < OFFD) {
      const float sq = sqrtf((float)(1 + 8 * col));
      const int i = (int)((1.f + sq) * 0.5f);
      const int tri = (i * (i - 1)) >> 1;
      const int r3 = i & 3;
      const int offv =
          tri + 6 * (i >> 2) + ((r3 == 2) ? 3 : (r3 == 3) ? 5 : 0) + (col - tri);
      const float bv = boo[col];
      const int padcnt = (4 - r3) & 3;
      const bool lastcol = (col == tri + i - 1);
#pragma unroll
      for (int fr = 0; fr < 8; ++fr) {
#pragma unroll
        for (int r = 0; r < 4; ++r) {
          const int srow = bm * 256 + wr * 128 + fr * 16 + lg * 4 + r;
          const int grp = srow >> 5, sig = srow & 31;
          const size_t pbase = (size_t)grp * GRP_UNITS + (sig >> 1) * 4224;
          zq[pbase + (size_t)offv * 2 + (sig & 1)] = (__bf16)(acc[fr][fc][r] + bv);
          if (lastcol && padcnt && ((r & 1) == 0)) {
            unsigned* pz = (unsigned*)(zq + pbase + (size_t)(offv + 1) * 2);
#pragma unroll
            for (int d = 0; d < 3; ++d)
              if (d < padcnt) pz[d] = 0u;
          }
        }
      }
    }
  }
}

// ---------------- apply: wave-local stage of one pair + two triangular passes ---
#define APPLY_SMEM (GRP_BYTES + 8192)
__global__ __launch_bounds__(1024) void apply_kernel(
    const __bf16* __restrict__ zq, const float* __restrict__ xd,
    const float* __restrict__ x0, float* __restrict__ out, int s0base) {
  extern __shared__ char smem[];
  __bf16* ztb = (__bf16*)smem;            // pair*4224 units + off*2 + slot
  float* ys2 = (float*)(smem + GRP_BYTES);

  const int tid = threadIdx.x;
  const int wave = tid >> 6, lane = tid & 63;
  const int sb = s0base + blockIdx.x * 32;
  const int s0 = wave * 2, s1 = s0 + 1;

  // issue x0/xd loads first (latency hides under the z stage)
  const float x0vA = x0[(size_t)(sb + s0) * 64 + lane];
  const float x0vB = x0[(size_t)(sb + s1) * 64 + lane];
  const float xdA = xd[(size_t)(sb + s0) * 64 + lane];
  const float xdB = xd[(size_t)(sb + s1) * 64 + lane];

  // stage this wave's pair slice (8448 B), wave-local, no barriers
  {
    const char* src = (const char*)zq + (size_t)blockIdx.x * GRP_BYTES + wave * 8448;
    char* dst = smem + wave * 8448;
#pragma unroll
    for (int j = 0; j < 8; ++j)
      gload_lds16(src + j * 1024 + lane * 16, dst + j * 1024);
    if (lane < 16) gload_lds16(src + 8192 + lane * 16, dst + 8192);
  }
  asm volatile("s_waitcnt vmcnt(0)" ::: "memory");
  SB0();

  const __bf16* zpair = ztb + wave * 4224;

  // pass 1: y_j = xd_j x0_j + sum_{k>j} z[k][j] x0_k  (one b32 read = both samples)
  float yA = xdA * x0vA, yB = xdB * x0vB;
  int rs = 0;
#pragma unroll
  for (int k = 1; k < 64; ++k) {
    const unsigned w = *(const unsigned*)(zpair + (rs + lane) * 2);
    const float xkA = lane_bcast(x0vA, k);
    const float xkB = lane_bcast(x0vB, k);
    const bool mvalid = lane < k;
    yA += mvalid ? bf_lo(w) * xkA : 0.f;
    yB += mvalid ? bf_hi(w) * xkB : 0.f;
    rs += (k + 3) & ~3;
  }

  // publish y (pair-interleaved), same wave consumes
  float* yp = ys2 + wave * 128;
  *(float2*)(yp + lane * 2) = make_float2(yA, yB);
  asm volatile("s_waitcnt lgkmcnt(0)" ::: "memory");
  SB0();

  // pass 2: D_i = xd_i y_i + sum_{j<i} z[i][j] y_j  (zero pads absorb masks)
  float DA = xdA * yA, DB = xdB * yB;
  float dA1 = 0.f, dB1 = 0.f;
  {
    const int r3 = lane & 3;
    const int rsi = ((lane * (lane - 1)) >> 1) + 6 * (lane >> 2) +
                    ((r3 == 2) ? 3 : (r3 == 3) ? 5 : 0);
    const int cmax = (lane + 3) >> 2;
    const __bf16* zrow = zpair + rsi * 2;
#pragma unroll 4
    for (int c = 0; c < cmax; ++c) {
      const uint4 w = *(const uint4*)(zrow + c * 8);
      const float4 u0 = *(const float4*)(yp + c * 8);
      const float4 u1 = *(const float4*)(yp + c * 8 + 4);
      DA += bf_lo(w.x) * u0.x + bf_lo(w.z) * u1.x;
      dA1 += bf_lo(w.y) * u0.z + bf_lo(w.w) * u1.z;
      DB += bf_hi(w.x) * u0.y + bf_hi(w.z) * u1.y;
      dB1 += bf_hi(w.y) * u0.w + bf_hi(w.w) * u1.w;
    }
  }
  out[(size_t)(sb + s0) * 64 + lane] = DA + dA1;
  out[(size_t)(sb + s1) * 64 + lane] = DB + dB1;
}

// ---------------- launch ----------------
extern "C" void kernel_launch(void* const* d_in, const int* in_sizes, int n_in,
                              void* d_out, int out_size, void* d_ws, size_t ws_size,
                              hipStream_t stream) {
  const float* x   = (const float*)d_in[0];
  const float* Wd1 = (const float*)d_in[1];
  const float* bd1 = (const float*)d_in[2];
  const float* Wd2 = (const float*)d_in[3];
  const float* bd2 = (const float*)d_in[4];
  const float* Wdo = (const float*)d_in[5];
  const float* bdo = (const float*)d_in[6];
  const float* Wo1 = (const float*)d_in[7];
  const float* bo1 = (const float*)d_in[8];
  const float* Wo2 = (const float*)d_in[9];
  const float* bo2 = (const float*)d_in[10];
  const float* Woo = (const float*)d_in[11];
  const float* boo = (const float*)d_in[12];
  float* out = (float*)d_out;

  char* ws = (char*)d_ws;
  __bf16* W1b  = (__bf16*)(ws + 0);          //    65536 B (Wd1 | Wo1 rows)
  __bf16* Wd2b = (__bf16*)(ws + 65536);      //   131072 B
  __bf16* Wo2b = (__bf16*)(ws + 196608);     //   131072 B
  __bf16* Wdob = (__bf16*)(ws + 327680);     //    32768 B
  __bf16* Woob = (__bf16*)(ws + 360448);     //  1048576 B (2048 rows, zero-padded)
  __bf16* g2   = (__bf16*)(ws + 1409024);    // 16777216 B
  float*  xdp  = (float*)(ws + 18186240);    //  8388608 B
  __bf16* zq   = (__bf16*)(ws + 26574848);   // 34603008 B (one quarter of z)

  cast_all_kernel<<<512, 256, 0, stream>>>(
      Wd1, W1b, HDIM * NDIM,
      Wo1, W1b + HDIM * NDIM, HDIM * NDIM,
      Wd2, Wd2b, HDIM * HDIM,
      Wo2, Wo2b, HDIM * HDIM,
      Wdo, Wdob, NDIM * HDIM,
      Woo, Woob, OFFD * HDIM,
      Woob + OFFD * HDIM, 32 * HDIM);

  trunk_kernel<<<B_TOT / 32, 512, 0, stream>>>(x, W1b, bd1, bo1, Wd2b, bd2, Wdob, bdo,
                                               Wo2b, bo2, g2, xdp);

  hipFuncSetAttribute((const void*)gemm_z_kernel,
                      hipFuncAttributeMaxDynamicSharedMemorySize, GEMM_SMEM);
  hipFuncSetAttribute((const void*)apply_kernel,
                      hipFuncAttributeMaxDynamicSharedMemorySize, APPLY_SMEM);
  for (int q = 0; q < 4; ++q) {
    gemm_z_kernel<<<(QS / 256) * 8, 512, GEMM_SMEM, stream>>>(
        g2 + (size_t)q * QS * HDIM, Woob, boo, zq);
    apply_kernel<<<QS / 32, 1024, APPLY_SMEM, stream>>>(zq, xdp, x, out, q * QS);
  }
}

// Round 10
// 197.431 us; speedup vs baseline: 1.2240x; 1.0750x over previous
//
#include <hip/hip_runtime.h>
#include <math.h>

// Damping: B=32768, N=64, H=256, OFF=2016
//   diag: x -> tanh(Wd1) -> tanh(Wd2) -> Wdo   (64 per sample)
//   off : x -> tanh(Wo1) -> tanh(Wo2) -> Woo   (2016 per sample, strict lower tri)
//   out = L (L^T x0), L diag = xd, L[i][j](j<i) = z[i(i-1)/2+j]

#define B_TOT 32768
#define NDIM  64
#define HDIM  256
#define OFFD  2016
#define QS    8192
#define GRP_UNITS 67584
#define GRP_BYTES 135168

typedef __bf16 bf16x8 __attribute__((ext_vector_type(8)));
typedef float  f32x4  __attribute__((ext_vector_type(4)));

__device__ __forceinline__ float fast_tanh(float x) {
  float e = __expf(2.f * x);
  return 1.f - 2.f * __builtin_amdgcn_rcpf(e + 1.f);
}
__device__ __forceinline__ float lane_bcast(float v, int l) {
  return __uint_as_float(__builtin_amdgcn_readlane(__float_as_uint(v), l));
}
__device__ __forceinline__ float bf_lo(unsigned w) { return __uint_as_float(w << 16); }
__device__ __forceinline__ float bf_hi(unsigned w) { return __uint_as_float(w & 0xffff0000u); }

__device__ __forceinline__ void gload_lds16(const void* g, void* l) {
  __builtin_amdgcn_global_load_lds(
      (const __attribute__((address_space(1))) unsigned*)g,
      (__attribute__((address_space(3))) unsigned*)l, 16, 0, 0);
}

#define MFMA(A, B, C) __builtin_amdgcn_mfma_f32_16x16x32_bf16((A), (B), (C), 0, 0, 0)
#define SB0() __builtin_amdgcn_sched_barrier(0)
// XOR-swizzled 16B-granule byte offset within a row (low 3 bits of granule)
#define GOFF(g, row) (((((g) & ~7) | (((g) & 7) ^ ((row) & 7)))) << 4)

// ---------------- weight cast (f32 -> bf16) + Woob pad zero-fill ----------------
__device__ __forceinline__ void cast_range(const float* __restrict__ s,
                                           __bf16* __restrict__ d, int n) {
  int i = blockIdx.x * blockDim.x + threadIdx.x;
  const int stride = gridDim.x * blockDim.x;
  for (; i < n; i += stride) d[i] = (__bf16)s[i];
}
__global__ __launch_bounds__(256) void cast_all_kernel(
    const float* s0, __bf16* d0, int n0, const float* s1, __bf16* d1, int n1,
    const float* s2, __bf16* d2, int n2, const float* s3, __bf16* d3, int n3,
    const float* s4, __bf16* d4, int n4, const float* s5, __bf16* d5, int n5,
    __bf16* d6, int n6) {
  cast_range(s0, d0, n0); cast_range(s1, d1, n1); cast_range(s2, d2, n2);
  cast_range(s3, d3, n3); cast_range(s4, d4, n4); cast_range(s5, d5, n5);
  int i = blockIdx.x * blockDim.x + threadIdx.x;
  const int stride = gridDim.x * blockDim.x;
  for (; i < n6; i += stride) d6[i] = (__bf16)0.f;
}

__device__ __forceinline__ bf16x8 cvt8(const float* __restrict__ p) {
  const float4 u = *(const float4*)p;
  const float4 v = *(const float4*)(p + 4);
  bf16x8 r;
  r[0] = (__bf16)u.x; r[1] = (__bf16)u.y; r[2] = (__bf16)u.z; r[3] = (__bf16)u.w;
  r[4] = (__bf16)v.x; r[5] = (__bf16)v.y; r[6] = (__bf16)v.z; r[7] = (__bf16)v.w;
  return r;
}

// ---------------- K1 v2: all-LDS trunk, 64 samples / WG, 8 waves ----------------
// Wcat chunks (16KB): [0,4)=W1(Wd1|Wo1,128B rows) [4,12)=Wo2 [12,20)=Wd2 [20,22)=Wdo
// LDS: xa 8KB (64 rows x 128B swz) | act 64KB (64 rows x 1KB swz; h1=g0..31,
//      g1/h2=g32..63) | wbuf 2x16KB
#define TRUNK_SMEM (8192 + 65536 + 32768)

__device__ __forceinline__ void stage_chunk(const char* Wcat, char* wb,
                                            int c, int buf, int wave) {
  const char* base = Wcat + (size_t)c * 16384;
  char* dst = wb + buf * 16384;
  const int lane = threadIdx.x & 63;
  const int s0 = wave * 64 + lane;
  const int s1 = s0 + 512;
  if (c < 4) {  // 128-byte rows (8 granules)
    const int r0 = s0 >> 3, q0 = (s0 & 7) ^ (r0 & 7);
    gload_lds16(base + r0 * 128 + (q0 << 4), dst + wave * 1024);
    const int r1 = s1 >> 3, q1 = (s1 & 7) ^ (r1 & 7);
    gload_lds16(base + r1 * 128 + (q1 << 4), dst + (wave + 8) * 1024);
  } else {      // 512-byte rows (32 granules)
    const int r0 = s0 >> 5, g0 = s0 & 31;
    const int q0 = (g0 & 24) | ((g0 & 7) ^ (r0 & 7));
    gload_lds16(base + r0 * 512 + (q0 << 4), dst + wave * 1024);
    const int r1 = s1 >> 5, g1 = s1 & 31;
    const int q1 = (g1 & 24) | ((g1 & 7) ^ (r1 & 7));
    gload_lds16(base + r1 * 512 + (q1 << 4), dst + (wave + 8) * 1024);
  }
}

__global__ __launch_bounds__(512, 2) void trunk_kernel(
    const float* __restrict__ x, const __bf16* __restrict__ Wcat,
    const float* __restrict__ bd1, const float* __restrict__ bo1,
    const float* __restrict__ bd2, const float* __restrict__ bo2,
    const float* __restrict__ bdo,
    __bf16* __restrict__ g2, float* __restrict__ xd) {
  extern __shared__ char smem[];
  char* xa  = smem;            // 8 KB
  char* act = smem + 8192;     // 64 KB
  char* wb  = smem + 73728;    // 32 KB
  const char* Wc = (const char*)Wcat;

  const int tid = threadIdx.x;
  const int wave = tid >> 6, lane = tid & 63;
  const int lr = lane & 15, lg = lane >> 4;
  const int sb = blockIdx.x * 64;

  // stage x -> xa (bf16, swizzled): thread t handles (s=t>>3, g=t&7)
  {
    const int s = tid >> 3, g = tid & 7;
    const bf16x8 v = cvt8(x + (size_t)(sb + s) * 64 + g * 8);
    *(bf16x8*)(xa + s * 128 + GOFF(g, s)) = v;
  }
  stage_chunk(Wc, wb, 0, 0, wave);
  __syncthreads();

  // ---- L1: 4 chunks of 128 rows; wave = n-tile within chunk ----
  for (int cc = 0; cc < 4; ++cc) {
    stage_chunk(Wc, wb, cc + 1, (cc + 1) & 1, wave);
    const char* wbp = wb + (cc & 1) * 16384;
    const int ch = cc * 128 + wave * 16 + lr;
    const float bv = (ch < 256) ? bd1[ch] : bo1[ch - 256];
    const int brow = wave * 16 + lr;
#pragma unroll
    for (int m = 0; m < 4; ++m) {
      const int arow = m * 16 + lr;
      f32x4 acc = {0.f, 0.f, 0.f, 0.f};
#pragma unroll
      for (int ks = 0; ks < 2; ++ks) {
        const int g = ks * 4 + lg;
        const bf16x8 a = *(const bf16x8*)(xa + arow * 128 + GOFF(g, arow));
        const bf16x8 b = *(const bf16x8*)(wbp + brow * 128 + GOFF(g, brow));
        acc = MFMA(a, b, acc);
      }
#pragma unroll
      for (int r = 0; r < 4; ++r) {
        const int s = m * 16 + lg * 4 + r;
        *(__bf16*)(act + s * 1024 + GOFF(ch >> 3, s) + (ch & 7) * 2) =
            (__bf16)fast_tanh(acc[r] + bv);
      }
    }
    __syncthreads();
  }

  // ---- L2o: 8 chunks of 32 rows (Wo2); reads g1 (g32..63) -> g2 global ----
  for (int cc = 0; cc < 8; ++cc) {
    const int gc = 4 + cc;
    stage_chunk(Wc, wb, gc + 1, (gc + 1) & 1, wave);
    const char* wbp = wb + (gc & 1) * 16384;
    const int m = wave >> 1, n = wave & 1;
    const int ch = cc * 32 + n * 16 + lr;
    const int brow = n * 16 + lr;
    const int arow = m * 16 + lr;
    f32x4 acc = {0.f, 0.f, 0.f, 0.f};
#pragma unroll
    for (int ks = 0; ks < 8; ++ks) {
      const int g = 32 + ks * 4 + lg;
      const bf16x8 a = *(const bf16x8*)(act + arow * 1024 + GOFF(g, arow));
      const bf16x8 b = *(const bf16x8*)(wbp + brow * 512 + GOFF(ks * 4 + lg, brow));
      acc = MFMA(a, b, acc);
    }
    const float bv = bo2[ch];
#pragma unroll
    for (int r = 0; r < 4; ++r) {
      const int s = m * 16 + lg * 4 + r;
      g2[(size_t)(sb + s) * 256 + ch] = (__bf16)fast_tanh(acc[r] + bv);
    }
    __syncthreads();
  }

  // ---- L2d: 8 chunks (Wd2); reads h1 (g0..31) -> h2 into g32..63 ----
  for (int cc = 0; cc < 8; ++cc) {
    const int gc = 12 + cc;
    stage_chunk(Wc, wb, gc + 1, (gc + 1) & 1, wave);
    const char* wbp = wb + (gc & 1) * 16384;
    const int m = wave >> 1, n = wave & 1;
    const int ch = cc * 32 + n * 16 + lr;
    const int brow = n * 16 + lr;
    const int arow = m * 16 + lr;
    f32x4 acc = {0.f, 0.f, 0.f, 0.f};
#pragma unroll
    for (int ks = 0; ks < 8; ++ks) {
      const int g = ks * 4 + lg;
      const bf16x8 a = *(const bf16x8*)(act + arow * 1024 + GOFF(g, arow));
      const bf16x8 b = *(const bf16x8*)(wbp + brow * 512 + GOFF(g, brow));
      acc = MFMA(a, b, acc);
    }
    const float bv = bd2[ch];
#pragma unroll
    for (int r = 0; r < 4; ++r) {
      const int s = m * 16 + lg * 4 + r;
      const int gd = 32 | (ch >> 3);
      *(__bf16*)(act + s * 1024 + GOFF(gd, s) + (ch & 7) * 2) =
          (__bf16)fast_tanh(acc[r] + bv);
    }
    __syncthreads();
  }

  // ---- L3: 2 chunks (Wdo); reads h2 (g32..63) -> xd global f32, no tanh ----
  for (int cc = 0; cc < 2; ++cc) {
    const int gc = 20 + cc;
    if (gc + 1 < 22) stage_chunk(Wc, wb, gc + 1, (gc + 1) & 1, wave);
    const char* wbp = wb + (gc & 1) * 16384;
    const int m = wave >> 1, n = wave & 1;
    const int ch = cc * 32 + n * 16 + lr;
    const int brow = n * 16 + lr;
    const int arow = m * 16 + lr;
    f32x4 acc = {0.f, 0.f, 0.f, 0.f};
#pragma unroll
    for (int ks = 0; ks < 8; ++ks) {
      const int g = 32 + ks * 4 + lg;
      const bf16x8 a = *(const bf16x8*)(act + arow * 1024 + GOFF(g, arow));
      const bf16x8 b = *(const bf16x8*)(wbp + brow * 512 + GOFF(ks * 4 + lg, brow));
      acc = MFMA(a, b, acc);
    }
    const float bv = bdo[ch];
#pragma unroll
    for (int r = 0; r < 4; ++r) {
      const int s = m * 16 + lg * 4 + r;
      xd[(size_t)(sb + s) * 64 + ch] = acc[r] + bv;
    }
    if (cc == 0) __syncthreads();
  }
}

// ---------------- gemm_z: z[8192 x 2016] = G @ Woo^T + boo  (per quarter) -------
#define TILE_BYTES 32768
#define GEMM_SMEM  131072

__global__ __launch_bounds__(512, 2) void gemm_z_kernel(
    const __bf16* __restrict__ g2q, const __bf16* __restrict__ Woob,
    const float* __restrict__ boo, __bf16* __restrict__ zq) {
  extern __shared__ char gsm[];
  const int tid = threadIdx.x;
  const int wave = tid >> 6, lane = tid & 63;
  const int lr = lane & 15, lg = lane >> 4;
  const int bm = blockIdx.x & 31, bn = blockIdx.x >> 5;
  const int wr = wave >> 2, wc = wave & 3;
  const int srl = lane >> 3;
  const int sch = lane & 7;

#define STAGE(BUF, KT)                                                          \
  {                                                                             \
    _Pragma("unroll")                                                           \
    for (int j = 0; j < 4; ++j) {                                               \
      const int row = wave * 32 + j * 8 + srl;                                  \
      const int ka = (KT) * 64 + ((sch ^ (row & 7)) << 3);                      \
      gload_lds16(g2q + (size_t)(bm * 256 + row) * 256 + ka,                    \
                  gsm + (BUF) * TILE_BYTES + wave * 4096 + j * 1024);           \
      gload_lds16(Woob + (size_t)(bn * 256 + row) * 256 + ka,                   \
                  gsm + 65536 + (BUF) * TILE_BYTES + wave * 4096 + j * 1024);   \
    }                                                                           \
  }

  f32x4 acc[8][4];
#pragma unroll
  for (int i = 0; i < 8; ++i)
#pragma unroll
    for (int j = 0; j < 4; ++j) acc[i][j] = (f32x4){0.f, 0.f, 0.f, 0.f};

  STAGE(0, 0)
  __syncthreads();
#pragma unroll
  for (int kt = 0; kt < 4; ++kt) {
    if (kt < 3) STAGE((kt + 1) & 1, kt + 1)
    const __bf16* Ab = (const __bf16*)(gsm + (kt & 1) * TILE_BYTES);
    const __bf16* Bb = (const __bf16*)(gsm + 65536 + (kt & 1) * TILE_BYTES);
#pragma unroll
    for (int ks = 0; ks < 2; ++ks) {
      const int cc = ((ks * 4 + lg) ^ (lr & 7)) << 3;
      bf16x8 af[8];
#pragma unroll
      for (int fr = 0; fr < 8; ++fr)
        af[fr] = *(const bf16x8*)(Ab + (wr * 128 + fr * 16 + lr) * 64 + cc);
      bf16x8 bfr[4];
#pragma unroll
      for (int fc = 0; fc < 4; ++fc)
        bfr[fc] = *(const bf16x8*)(Bb + (wc * 64 + fc * 16 + lr) * 64 + cc);
#pragma unroll
      for (int fr = 0; fr < 8; ++fr)
#pragma unroll
        for (int fc = 0; fc < 4; ++fc)
          acc[fr][fc] = MFMA(af[fr], bfr[fc], acc[fr][fc]);
    }
    if (kt < 3) __syncthreads();
  }

  // epilogue: scatter into padded-triangle pair-interleaved z (+ pad zeros)
#pragma unroll
  for (int fc = 0; fc < 4; ++fc) {
    const int col = bn * 256 + wc * 64 + fc * 16 + lr;
    if (col < OFFD) {
      const float sq = sqrtf((float)(1 + 8 * col));
      const int i = (int)((1.f + sq) * 0.5f);
      const int tri = (i * (i - 1)) >> 1;
      const int r3 = i & 3;
      const int offv =
          tri + 6 * (i >> 2) + ((r3 == 2) ? 3 : (r3 == 3) ? 5 : 0) + (col - tri);
      const float bv = boo[col];
      const int padcnt = (4 - r3) & 3;
      const bool lastcol = (col == tri + i - 1);
#pragma unroll
      for (int fr = 0; fr < 8; ++fr) {
#pragma unroll
        for (int r = 0; r < 4; ++r) {
          const int srow = bm * 256 + wr * 128 + fr * 16 + lg * 4 + r;
          const int grp = srow >> 5, sig = srow & 31;
          const size_t pbase = (size_t)grp * GRP_UNITS + (sig >> 1) * 4224;
          zq[pbase + (size_t)offv * 2 + (sig & 1)] = (__bf16)(acc[fr][fc][r] + bv);
          if (lastcol && padcnt && ((r & 1) == 0)) {
            unsigned* pz = (unsigned*)(zq + pbase + (size_t)(offv + 1) * 2);
#pragma unroll
            for (int d = 0; d < 3; ++d)
              if (d < padcnt) pz[d] = 0u;
          }
        }
      }
    }
  }
}

// ---------------- apply: wave-local stage of one pair + two triangular passes ---
#define APPLY_SMEM (GRP_BYTES + 8192)
__global__ __launch_bounds__(1024) void apply_kernel(
    const __bf16* __restrict__ zq, const float* __restrict__ xd,
    const float* __restrict__ x0, float* __restrict__ out, int s0base) {
  extern __shared__ char smem[];
  __bf16* ztb = (__bf16*)smem;
  float* ys2 = (float*)(smem + GRP_BYTES);

  const int tid = threadIdx.x;
  const int wave = tid >> 6, lane = tid & 63;
  const int sb = s0base + blockIdx.x * 32;
  const int s0 = wave * 2, s1 = s0 + 1;

  const float x0vA = x0[(size_t)(sb + s0) * 64 + lane];
  const float x0vB = x0[(size_t)(sb + s1) * 64 + lane];
  const float xdA = xd[(size_t)(sb + s0) * 64 + lane];
  const float xdB = xd[(size_t)(sb + s1) * 64 + lane];

  {
    const char* src = (const char*)zq + (size_t)blockIdx.x * GRP_BYTES + wave * 8448;
    char* dst = smem + wave * 8448;
#pragma unroll
    for (int j = 0; j < 8; ++j)
      gload_lds16(src + j * 1024 + lane * 16, dst + j * 1024);
    if (lane < 16) gload_lds16(src + 8192 + lane * 16, dst + 8192);
  }
  asm volatile("s_waitcnt vmcnt(0)" ::: "memory");
  SB0();

  const __bf16* zpair = ztb + wave * 4224;

  float yA = xdA * x0vA, yB = xdB * x0vB;
  int rs = 0;
#pragma unroll
  for (int k = 1; k < 64; ++k) {
    const unsigned w = *(const unsigned*)(zpair + (rs + lane) * 2);
    const float xkA = lane_bcast(x0vA, k);
    const float xkB = lane_bcast(x0vB, k);
    const bool mvalid = lane < k;
    yA += mvalid ? bf_lo(w) * xkA : 0.f;
    yB += mvalid ? bf_hi(w) * xkB : 0.f;
    rs += (k + 3) & ~3;
  }

  float* yp = ys2 + wave * 128;
  *(float2*)(yp + lane * 2) = make_float2(yA, yB);
  asm volatile("s_waitcnt lgkmcnt(0)" ::: "memory");
  SB0();

  float DA = xdA * yA, DB = xdB * yB;
  float dA1 = 0.f, dB1 = 0.f;
  {
    const int r3 = lane & 3;
    const int rsi = ((lane * (lane - 1)) >> 1) + 6 * (lane >> 2) +
                    ((r3 == 2) ? 3 : (r3 == 3) ? 5 : 0);
    const int cmax = (lane + 3) >> 2;
    const __bf16* zrow = zpair + rsi * 2;
#pragma unroll 4
    for (int c = 0; c < cmax; ++c) {
      const uint4 w = *(const uint4*)(zrow + c * 8);
      const float4 u0 = *(const float4*)(yp + c * 8);
      const float4 u1 = *(const float4*)(yp + c * 8 + 4);
      DA += bf_lo(w.x) * u0.x + bf_lo(w.z) * u1.x;
      dA1 += bf_lo(w.y) * u0.z + bf_lo(w.w) * u1.z;
      DB += bf_hi(w.x) * u0.y + bf_hi(w.z) * u1.y;
      dB1 += bf_hi(w.y) * u0.w + bf_hi(w.w) * u1.w;
    }
  }
  out[(size_t)(sb + s0) * 64 + lane] = DA + dA1;
  out[(size_t)(sb + s1) * 64 + lane] = DB + dB1;
}

// ---------------- launch ----------------
extern "C" void kernel_launch(void* const* d_in, const int* in_sizes, int n_in,
                              void* d_out, int out_size, void* d_ws, size_t ws_size,
                              hipStream_t stream) {
  const float* x   = (const float*)d_in[0];
  const float* Wd1 = (const float*)d_in[1];
  const float* bd1 = (const float*)d_in[2];
  const float* Wd2 = (const float*)d_in[3];
  const float* bd2 = (const float*)d_in[4];
  const float* Wdo = (const float*)d_in[5];
  const float* bdo = (const float*)d_in[6];
  const float* Wo1 = (const float*)d_in[7];
  const float* bo1 = (const float*)d_in[8];
  const float* Wo2 = (const float*)d_in[9];
  const float* bo2 = (const float*)d_in[10];
  const float* Woo = (const float*)d_in[11];
  const float* boo = (const float*)d_in[12];
  float* out = (float*)d_out;

  char* ws = (char*)d_ws;
  // Wcat layout (bf16 elems): Wd1@0, Wo1@16384, Wo2@32768, Wd2@98304, Wdo@163840
  __bf16* Wcat = (__bf16*)(ws + 0);          //   360448 B
  __bf16* Woob = (__bf16*)(ws + 360448);     //  1048576 B (2048 rows, zero-padded)
  __bf16* g2   = (__bf16*)(ws + 1409024);    // 16777216 B
  float*  xdp  = (float*)(ws + 18186240);    //  8388608 B
  __bf16* zq   = (__bf16*)(ws + 26574848);   // 34603008 B

  cast_all_kernel<<<512, 256, 0, stream>>>(
      Wd1, Wcat, HDIM * NDIM,
      Wo1, Wcat + 16384, HDIM * NDIM,
      Wo2, Wcat + 32768, HDIM * HDIM,
      Wd2, Wcat + 98304, HDIM * HDIM,
      Wdo, Wcat + 163840, NDIM * HDIM,
      Woo, Woob, OFFD * HDIM,
      Woob + OFFD * HDIM, 32 * HDIM);

  hipFuncSetAttribute((const void*)trunk_kernel,
                      hipFuncAttributeMaxDynamicSharedMemorySize, TRUNK_SMEM);
  trunk_kernel<<<B_TOT / 64, 512, TRUNK_SMEM, stream>>>(
      x, Wcat, bd1, bo1, bd2, bo2, bdo, g2, xdp);

  hipFuncSetAttribute((const void*)gemm_z_kernel,
                      hipFuncAttributeMaxDynamicSharedMemorySize, GEMM_SMEM);
  hipFuncSetAttribute((const void*)apply_kernel,
                      hipFuncAttributeMaxDynamicSharedMemorySize, APPLY_SMEM);
  for (int q = 0; q < 4; ++q) {
    gemm_z_kernel<<<(QS / 256) * 8, 512, GEMM_SMEM, stream>>>(
        g2 + (size_t)q * QS * HDIM, Woob, boo, zq);
    apply_kernel<<<QS / 32, 1024, APPLY_SMEM, stream>>>(zq, xdp, x, out, q * QS);
  }
}